// Round 1
// baseline (1283.275 us; speedup 1.0000x reference)
//
#include <hip/hip_runtime.h>
#include <hip/hip_bf16.h>

// Fused multimodal attention block for MI355X (gfx950).
// Pipeline: cvt(f32->bf16) -> per-modality QKV GEMM (bf16 MFMA) ->
//           in-place RMSNorm+RoPE on q,k -> block-diagonal GQA flash attn ->
//           per-modality out GEMM (fp32 out).

typedef __bf16 bf16;
typedef __attribute__((ext_vector_type(8))) __bf16 bf16x8;
typedef __attribute__((ext_vector_type(4))) __bf16 bf16x4;
typedef __attribute__((ext_vector_type(4))) float f32x4;

#define S_TOT 8192
#define HID 3072
#define NHQ 24
#define NHKV 8
#define HD 128
#define QKV_OUT 5120  // (24 + 2*8) * 128
#define CHUNKT 1024

__device__ inline void gload_lds16(const void* g, void* l) {
  __builtin_amdgcn_global_load_lds((const __attribute__((address_space(1))) void*)g,
                                   (__attribute__((address_space(3))) void*)l, 16, 0, 0);
}

__device__ inline f32x4 mfma16(bf16x8 a, bf16x8 b, f32x4 c) {
  return __builtin_amdgcn_mfma_f32_16x16x32_bf16(a, b, c, 0, 0, 0);
}

// ---------------- f32 -> bf16 convert ----------------
__global__ __launch_bounds__(256) void cvt_kernel(const float* __restrict__ in,
                                                  bf16* __restrict__ out, int n4) {
  int idx = blockIdx.x * 256 + threadIdx.x;
  int stride = gridDim.x * 256;
  for (int i = idx; i < n4; i += stride) {
    float4 v = reinterpret_cast<const float4*>(in)[i];
    bf16x4 o = {(bf16)v.x, (bf16)v.y, (bf16)v.z, (bf16)v.w};
    reinterpret_cast<bf16x4*>(out)[i] = o;
  }
}

// ---------------- BT-GEMM: C[M,N] = A[M,K] * B[N,K]^T + bias ----------------
// m97-style 128x128 tile, BK=64, 4 waves, global_load_lds staging.
// grid: (N/128, M/128, 2 modalities)
template <int OUT_BF16>
__global__ __launch_bounds__(256) void gemm_bt(const bf16* __restrict__ A,
                                               const bf16* __restrict__ B,
                                               const float* __restrict__ bias,
                                               void* __restrict__ Cv,
                                               int M, int N, int K) {
  const int mz = blockIdx.z;
  A += (size_t)mz * M * K;
  B += (size_t)mz * N * K;
  bias += (size_t)mz * N;
  bf16* Cb = (bf16*)Cv + (size_t)mz * M * N;
  float* Cf = (float*)Cv + (size_t)mz * M * N;

  __shared__ bf16 As[128 * 64];
  __shared__ bf16 Bs[128 * 64];

  const int tid = threadIdx.x;
  const int l = tid & 63;
  const int w = tid >> 6;
  const int wr = w >> 1, wc = w & 1;

  const bf16* Abase = A + (size_t)(blockIdx.y * 128) * K;
  const bf16* Bbase = B + (size_t)(blockIdx.x * 128) * K;

  f32x4 acc[4][4] = {};

  for (int k0 = 0; k0 < K; k0 += 64) {
#pragma unroll
    for (int it = 0; it < 4; ++it) {
      int idx = it * 256 + tid;
      int row = idx >> 3, c8 = idx & 7;
      gload_lds16(Abase + (size_t)row * K + k0 + c8 * 8, &As[idx * 8]);
    }
#pragma unroll
    for (int it = 0; it < 4; ++it) {
      int idx = it * 256 + tid;
      int row = idx >> 3, c8 = idx & 7;
      gload_lds16(Bbase + (size_t)row * K + k0 + c8 * 8, &Bs[idx * 8]);
    }
    __syncthreads();
#pragma unroll
    for (int kk = 0; kk < 64; kk += 32) {
      bf16x8 a[4], b[4];
#pragma unroll
      for (int i = 0; i < 4; ++i)
        a[i] = *reinterpret_cast<const bf16x8*>(
            &As[(wr * 64 + i * 16 + (l & 15)) * 64 + kk + (l >> 4) * 8]);
#pragma unroll
      for (int j = 0; j < 4; ++j)
        b[j] = *reinterpret_cast<const bf16x8*>(
            &Bs[(wc * 64 + j * 16 + (l & 15)) * 64 + kk + (l >> 4) * 8]);
#pragma unroll
      for (int i = 0; i < 4; ++i)
#pragma unroll
        for (int j = 0; j < 4; ++j)
          acc[i][j] = mfma16(a[i], b[j], acc[i][j]);
    }
    __syncthreads();
  }

  // C/D layout: col = l&15, row = (l>>4)*4 + r   [guide §3, m89-verified]
  const int row0 = blockIdx.y * 128 + wr * 64 + ((l >> 4) << 2);
  const int col0 = blockIdx.x * 128 + wc * 64 + (l & 15);
#pragma unroll
  for (int j = 0; j < 4; ++j) {
    int col = col0 + j * 16;
    float bv = bias[col];
#pragma unroll
    for (int i = 0; i < 4; ++i) {
#pragma unroll
      for (int r = 0; r < 4; ++r) {
        int row = row0 + i * 16 + r;
        float v = acc[i][j][r] + bv;
        if (OUT_BF16)
          Cb[(size_t)row * N + col] = (bf16)v;
        else
          Cf[(size_t)row * N + col] = v;
      }
    }
  }
}

// ---------------- in-place RMSNorm + RoPE on q,k head rows ----------------
// one wave per (token, head) row of 128; v rows untouched.
__global__ __launch_bounds__(256) void rmsrope_kernel(bf16* __restrict__ qkv,
                                                      const float* __restrict__ qw,
                                                      const float* __restrict__ kw,
                                                      const float* __restrict__ cosT,
                                                      const float* __restrict__ sinT) {
  int gid = blockIdx.x * 4 + (threadIdx.x >> 6);
  int l = threadIdx.x & 63;
  int tok = gid >> 5;   // 32 (q+k) head rows per token
  int slot = gid & 31;
  int mz = tok >> 12;   // 4096 tokens per modality
  bf16* p;
  const float* wv;
  if (slot < NHQ) {
    p = qkv + (size_t)tok * QKV_OUT + slot * HD;
    wv = qw + mz * HD;
  } else {
    p = qkv + (size_t)tok * QKV_OUT + HID + (slot - NHQ) * HD;
    wv = kw + mz * HD;
  }
  int d = l * 2;
  float x0 = (float)p[d];
  float x1 = (float)p[d + 1];
  float ss = x0 * x0 + x1 * x1;
#pragma unroll
  for (int m = 1; m < 64; m <<= 1) ss += __shfl_xor(ss, m);
  float rn = rsqrtf(ss * (1.0f / 128.0f) + 1e-6f);
  float n0 = x0 * rn * (wv[d] + 1.0f);
  float n1 = x1 * rn * (wv[d + 1] + 1.0f);
  // rotate_half partner: d<64 pairs with d+64 (same intra-pair position)
  float o0 = __shfl_xor(n0, 32);
  float o1 = __shfl_xor(n1, 32);
  int ci = d & 63;
  float2 cv = *reinterpret_cast<const float2*>(cosT + (size_t)tok * 64 + ci);
  float2 sv = *reinterpret_cast<const float2*>(sinT + (size_t)tok * 64 + ci);
  float sgn = (l < 32) ? -1.0f : 1.0f;
  p[d] = (bf16)(n0 * cv.x + sgn * o0 * sv.x);
  p[d + 1] = (bf16)(n1 * cv.y + sgn * o1 * sv.y);
}

// ---------------- block-diagonal GQA flash attention ----------------
// grid: (8 q-subtiles, 24 heads, 8 token-blocks); 4 waves x 32 q-rows.
// K chunk (128x128) in KP (aliased by P after a barrier), V chunk transposed in Vt.
__global__ __launch_bounds__(256) void attn_kernel(const bf16* __restrict__ qkv,
                                                   bf16* __restrict__ o) {
  constexpr float CEXP = 0.12753139626334912f;  // log2(e)/sqrt(128)
  const int tid = threadIdx.x;
  const int l = tid & 63;
  const int w = tid >> 6;
  const int sq = blockIdx.x;
  const int h = blockIdx.y;
  const int blk = blockIdx.z;
  const int kvh = h / 3;
  const int qtok0 = blk * CHUNKT + sq * 128 + w * 32;
  const int ktok0 = blk * CHUNKT;

  __shared__ bf16 KP[128 * 136];  // K chunk; reused as P (per-wave 32-row slices)
  __shared__ bf16 Vt[128 * 136];  // V chunk transposed: Vt[d][key]

  // Q fragments in registers: rows = qtok0 + i*16 + (l&15), k = c*32 + (l>>4)*8
  bf16x8 qf[2][4];
#pragma unroll
  for (int i = 0; i < 2; ++i) {
    const bf16* qp =
        qkv + (size_t)(qtok0 + i * 16 + (l & 15)) * QKV_OUT + h * HD + (l >> 4) * 8;
#pragma unroll
    for (int c = 0; c < 4; ++c) qf[i][c] = *reinterpret_cast<const bf16x8*>(qp + c * 32);
  }

  f32x4 of[2][8] = {};
  float mrow[2][4], lrow[2][4];
#pragma unroll
  for (int i = 0; i < 2; ++i)
#pragma unroll
    for (int r = 0; r < 4; ++r) {
      mrow[i][r] = -1e30f;
      lrow[i][r] = 0.0f;
    }

  for (int c = 0; c < 8; ++c) {
    __syncthreads();  // prior PV reads of KP(P)/Vt complete before restage
    const int kt = ktok0 + c * 128;
    // stage K rows (coalesced 16B, conflict-free b128 LDS writes)
#pragma unroll
    for (int it = 0; it < 8; ++it) {
      int task = it * 256 + tid;
      int key = task >> 4, dc = task & 15;
      *reinterpret_cast<bf16x8*>(&KP[key * 136 + dc * 8]) =
          *reinterpret_cast<const bf16x8*>(
              qkv + (size_t)(kt + key) * QKV_OUT + HID + kvh * HD + dc * 8);
    }
    // stage V transposed (lanes on consecutive keys -> conflict-free b16 writes)
#pragma unroll
    for (int it = 0; it < 8; ++it) {
      int task = it * 256 + tid;
      int key = task & 127, dc = task >> 7;
      bf16x8 vv = *reinterpret_cast<const bf16x8*>(
          qkv + (size_t)(kt + key) * QKV_OUT + HID + NHKV * HD + kvh * HD + dc * 8);
#pragma unroll
      for (int jj = 0; jj < 8; ++jj) Vt[(dc * 8 + jj) * 136 + key] = vv[jj];
    }
    __syncthreads();

    // S = Q * K^T (raw dots; scale folded into exp)
    f32x4 sacc[2][8] = {};
#pragma unroll
    for (int kd = 0; kd < 4; ++kd) {
      bf16x8 kb[8];
#pragma unroll
      for (int j = 0; j < 8; ++j)
        kb[j] = *reinterpret_cast<const bf16x8*>(
            &KP[(j * 16 + (l & 15)) * 136 + kd * 32 + (l >> 4) * 8]);
#pragma unroll
      for (int i = 0; i < 2; ++i)
#pragma unroll
        for (int j = 0; j < 8; ++j) sacc[i][j] = mfma16(qf[i][kd], kb[j], sacc[i][j]);
    }

    // online softmax; row owned by 16-lane group (row = (l>>4)*4 + r)
    float alpha[2][4];
#pragma unroll
    for (int i = 0; i < 2; ++i) {
#pragma unroll
      for (int r = 0; r < 4; ++r) {
        float mx = sacc[i][0][r];
#pragma unroll
        for (int j = 1; j < 8; ++j) mx = fmaxf(mx, sacc[i][j][r]);
        mx = fmaxf(mx, __shfl_xor(mx, 1));
        mx = fmaxf(mx, __shfl_xor(mx, 2));
        mx = fmaxf(mx, __shfl_xor(mx, 4));
        mx = fmaxf(mx, __shfl_xor(mx, 8));
        float mnew = fmaxf(mrow[i][r], mx);
        float al = exp2f((mrow[i][r] - mnew) * CEXP);
        mrow[i][r] = mnew;
        float ps = 0.0f;
#pragma unroll
        for (int j = 0; j < 8; ++j) {
          float pv = exp2f((sacc[i][j][r] - mnew) * CEXP);
          sacc[i][j][r] = pv;
          ps += pv;
        }
        ps += __shfl_xor(ps, 1);
        ps += __shfl_xor(ps, 2);
        ps += __shfl_xor(ps, 4);
        ps += __shfl_xor(ps, 8);
        lrow[i][r] = lrow[i][r] * al + ps;
        alpha[i][r] = al;
      }
    }
#pragma unroll
    for (int i = 0; i < 2; ++i)
#pragma unroll
      for (int j = 0; j < 8; ++j)
#pragma unroll
        for (int r = 0; r < 4; ++r) of[i][j][r] *= alpha[i][r];

    __syncthreads();  // all waves done reading K before P overwrites KP
    bf16* P = KP + w * (32 * 136);
#pragma unroll
    for (int i = 0; i < 2; ++i)
#pragma unroll
      for (int j = 0; j < 8; ++j)
#pragma unroll
        for (int r = 0; r < 4; ++r)
          P[(i * 16 + (l >> 4) * 4 + r) * 136 + j * 16 + (l & 15)] = (bf16)sacc[i][j][r];

    // O += P * V  (A=P from LDS, B from Vt rows: key-contiguous)
#pragma unroll
    for (int kk = 0; kk < 4; ++kk) {
      bf16x8 pa[2];
#pragma unroll
      for (int i = 0; i < 2; ++i)
        pa[i] = *reinterpret_cast<const bf16x8*>(
            &P[(i * 16 + (l & 15)) * 136 + kk * 32 + (l >> 4) * 8]);
#pragma unroll
      for (int j = 0; j < 8; ++j) {
        bf16x8 bv = *reinterpret_cast<const bf16x8*>(
            &Vt[(j * 16 + (l & 15)) * 136 + kk * 32 + (l >> 4) * 8]);
        of[0][j] = mfma16(pa[0], bv, of[0][j]);
        of[1][j] = mfma16(pa[1], bv, of[1][j]);
      }
    }
  }

#pragma unroll
  for (int i = 0; i < 2; ++i) {
#pragma unroll
    for (int r = 0; r < 4; ++r) {
      float inv = 1.0f / lrow[i][r];
      int row = qtok0 + i * 16 + (l >> 4) * 4 + r;
      bf16* orow = o + (size_t)row * HID + h * HD + (l & 15);
#pragma unroll
      for (int j = 0; j < 8; ++j) orow[j * 16] = (bf16)(of[i][j][r] * inv);
    }
  }
}

extern "C" void kernel_launch(void* const* d_in, const int* in_sizes, int n_in,
                              void* d_out, int out_size, void* d_ws, size_t ws_size,
                              hipStream_t stream) {
  const float* x = (const float*)d_in[0];
  const float* wqkv = (const float*)d_in[1];
  const float* bqkv = (const float*)d_in[2];
  const float* qnw = (const float*)d_in[3];
  const float* knw = (const float*)d_in[4];
  const float* cosT = (const float*)d_in[5];
  const float* sinT = (const float*)d_in[6];
  const float* wout = (const float*)d_in[7];
  const float* bout = (const float*)d_in[8];
  float* out = (float*)d_out;

  // ws layout (bytes):
  //   region A: xb (S*HID bf16, 50.3MB)  -> reused as attention output ob
  //   region B: wqkvb (2*5120*3072 bf16, 62.9MB) -> reused as woutb
  //   region C: qkv (S*5120 bf16, 83.9MB)
  char* ws = (char*)d_ws;
  bf16* xb = (bf16*)ws;
  ws += (size_t)S_TOT * HID * 2;
  bf16* wqkvb = (bf16*)ws;
  ws += (size_t)2 * QKV_OUT * HID * 2;
  bf16* qkv = (bf16*)ws;
  bf16* ob = xb;       // region A reuse
  bf16* woutb = wqkvb; // region B reuse (converted after qkv GEMM consumed it)

  cvt_kernel<<<2048, 256, 0, stream>>>(x, xb, S_TOT * HID / 4);
  cvt_kernel<<<2048, 256, 0, stream>>>(wqkv, wqkvb, 2 * QKV_OUT * HID / 4);

  gemm_bt<1><<<dim3(QKV_OUT / 128, 4096 / 128, 2), 256, 0, stream>>>(
      xb, wqkvb, bqkv, qkv, 4096, QKV_OUT, HID);

  cvt_kernel<<<2048, 256, 0, stream>>>(wout, woutb, 2 * HID * HID / 4);

  rmsrope_kernel<<<(S_TOT * (NHQ + NHKV)) / 4, 256, 0, stream>>>(qkv, qnw, knw, cosT, sinT);

  attn_kernel<<<dim3(8, NHQ, 8), 256, 0, stream>>>(qkv, ob);

  gemm_bt<0><<<dim3(HID / 128, 4096 / 128, 2), 256, 0, stream>>>(
      ob, woutb, bout, out, 4096, HID, HID);
}

// Round 6
// 1135.576 us; speedup vs baseline: 1.1301x; 1.1301x over previous
//
#include <hip/hip_runtime.h>
#include <hip/hip_bf16.h>

// Fused multimodal attention block for MI355X (gfx950).
// cvt(f32->bf16) -> per-modality QKV GEMM (256^2 8-phase bf16 MFMA) ->
// in-place RMSNorm+RoPE -> block-diagonal GQA flash attn -> out GEMM (fp32).

typedef __bf16 bf16;
typedef __attribute__((ext_vector_type(8))) __bf16 bf16x8;
typedef __attribute__((ext_vector_type(4))) __bf16 bf16x4;
typedef __attribute__((ext_vector_type(4))) float f32x4;

#define S_TOT 8192
#define HID 3072
#define NHQ 24
#define NHKV 8
#define HD 128
#define QKV_OUT 5120  // (24 + 2*8) * 128
#define CHUNKT 1024

__device__ inline void gload_lds16(const void* g, void* l) {
  __builtin_amdgcn_global_load_lds((const __attribute__((address_space(1))) void*)g,
                                   (__attribute__((address_space(3))) void*)l, 16, 0, 0);
}

__device__ inline f32x4 mfma16(bf16x8 a, bf16x8 b, f32x4 c) {
  return __builtin_amdgcn_mfma_f32_16x16x32_bf16(a, b, c, 0, 0, 0);
}

// ---------------- f32 -> bf16 convert ----------------
__global__ __launch_bounds__(256) void cvt_kernel(const float* __restrict__ in,
                                                  bf16* __restrict__ out, int n4) {
  int idx = blockIdx.x * 256 + threadIdx.x;
  int stride = gridDim.x * 256;
  for (int i = idx; i < n4; i += stride) {
    float4 v = reinterpret_cast<const float4*>(in)[i];
    bf16x4 o = {(bf16)v.x, (bf16)v.y, (bf16)v.z, (bf16)v.w};
    reinterpret_cast<bf16x4*>(out)[i] = o;
  }
}

// ---------------- 256x256 8-phase BT-GEMM: C[M,N] = A[M,K]*B[N,K]^T + bias --
// 8 waves (2x4), BK=64, 128KiB double-buffered LDS, XOR-swizzled (row&7)<<4,
// counted vmcnt(6), setprio around MFMA clusters. Requires M%256==N%256==0,
// K%64==0, grid = (M/256)*(N/256)*2 with grid%8==0.
template <int OUT_BF16>
__global__ __launch_bounds__(512, 2) void gemm256(const bf16* __restrict__ A,
                                                  const bf16* __restrict__ B,
                                                  const float* __restrict__ bias,
                                                  void* __restrict__ Cv,
                                                  int M, int N, int K) {
  __shared__ bf16 lds[65536];  // A0|A1|B0|B1, each 16384 elems (32 KiB)
  const int tid = threadIdx.x;
  const int l = tid & 63;
  const int w = tid >> 6;
  const int wr = w >> 2, wc = w & 3;
  const int lm = l & 15, lg = l >> 4;

  // bijective XCD swizzle (gridDim.x % 8 == 0)
  const int nwg = gridDim.x;
  const int id = blockIdx.x;
  const int swzid = (id & 7) * (nwg >> 3) + (id >> 3);
  const int xt = N >> 8, yt = M >> 8;
  const int bn = swzid % xt;
  const int rem = swzid / xt;
  const int bm = rem % yt;
  const int mz = rem / yt;

  const bf16* Ag = A + (size_t)mz * M * K + (size_t)(bm * 256) * K;
  const bf16* Bg = B + (size_t)mz * N * K + (size_t)(bn * 256) * K;
  const float* biasg = bias + (size_t)mz * N;

  // staging: 1 load/thread per 64x64 quarter; linear LDS dest, inverse-swizzled src
  const int srow = tid >> 3;                               // row within quarter
  const int scolb = ((tid & 7) * 16) ^ ((srow & 7) << 4);  // logical byte col
  const bf16* Asrc = Ag + (size_t)srow * K + (scolb >> 1);
  const bf16* Bsrc = Bg + (size_t)srow * K + (scolb >> 1);
  bf16* ldsA = lds;
  bf16* ldsB = lds + 32768;

  auto stA = [&](int buf, int q, int t) {
    gload_lds16(Asrc + (size_t)(q * 64) * K + t * 64,
                ldsA + buf * 16384 + q * 4096 + tid * 8);
  };
  auto stB = [&](int buf, int q, int t) {
    gload_lds16(Bsrc + (size_t)(q * 64) * K + t * 64,
                ldsB + buf * 16384 + q * 4096 + tid * 8);
  };

  // swizzled ds_read bases (row = i*16+lm -> row&7 == lm&7, per-lane constant)
  const int xmb = (lm & 7) << 4;
  const int cb0 = (lg * 16) ^ xmb;  // kk=0 byte col
  const int cb1 = cb0 ^ 64;        // kk=32 byte col
  const int aoff0 = (wr * 128 + lm) * 64 + (cb0 >> 1);
  const int aoff1 = (wr * 128 + lm) * 64 + (cb1 >> 1);
  const int boff0 = (wc * 64 + lm) * 64 + (cb0 >> 1);
  const int boff1 = (wc * 64 + lm) * 64 + (cb1 >> 1);

  const int NT = K >> 6;
  f32x4 acc[8][4] = {};

  // prologue: tile0 full (8 quarters) -> buf0; tile1 Aq0-3,Bq0,Bq1 -> buf1
#pragma unroll
  for (int q = 0; q < 4; ++q) stA(0, q, 0);
#pragma unroll
  for (int q = 0; q < 4; ++q) stB(0, q, 0);
#pragma unroll
  for (int q = 0; q < 4; ++q) stA(1, q, 1);
  stB(1, 0, 1);
  stB(1, 1, 1);
  asm volatile("s_waitcnt vmcnt(6)" ::: "memory");  // tile0 landed
  __builtin_amdgcn_s_barrier();

  for (int T = 0; T < NT; ++T) {
    const int cbuf = T & 1, nbuf = cbuf ^ 1;
    const bf16* Ac = ldsA + cbuf * 16384;
    const bf16* Bc = ldsB + cbuf * 16384;
    const bool s1 = (T + 1) < NT;
    const bool s2 = (T + 2) < NT;
    bf16x8 alo[4][2], ahi[4][2], blo[2][2], bhi[2][2];

    // ---- phase 1: read a[0..3], b[0..1]; stage (T+1) Bq2,Bq3 ----
#pragma unroll
    for (int i = 0; i < 4; ++i) {
      alo[i][0] = *(const bf16x8*)(Ac + aoff0 + i * 1024);
      alo[i][1] = *(const bf16x8*)(Ac + aoff1 + i * 1024);
    }
#pragma unroll
    for (int j = 0; j < 2; ++j) {
      blo[j][0] = *(const bf16x8*)(Bc + boff0 + j * 1024);
      blo[j][1] = *(const bf16x8*)(Bc + boff1 + j * 1024);
    }
    if (s1) { stB(nbuf, 2, T + 1); stB(nbuf, 3, T + 1); }
    __builtin_amdgcn_s_barrier();
    asm volatile("s_waitcnt lgkmcnt(0)" ::: "memory");
    __builtin_amdgcn_s_setprio(1);
#pragma unroll
    for (int i = 0; i < 4; ++i)
#pragma unroll
      for (int j = 0; j < 2; ++j) {
        acc[i][j] = mfma16(alo[i][0], blo[j][0], acc[i][j]);
        acc[i][j] = mfma16(alo[i][1], blo[j][1], acc[i][j]);
      }
    __builtin_amdgcn_s_setprio(0);
    __builtin_amdgcn_s_barrier();

    // ---- phase 2: read b[2..3]; stage (T+2) Aq0,Aq2 ----
#pragma unroll
    for (int j = 0; j < 2; ++j) {
      bhi[j][0] = *(const bf16x8*)(Bc + boff0 + (j + 2) * 1024);
      bhi[j][1] = *(const bf16x8*)(Bc + boff1 + (j + 2) * 1024);
    }
    if (s2) { stA(cbuf, 0, T + 2); stA(cbuf, 2, T + 2); }
    __builtin_amdgcn_s_barrier();
    asm volatile("s_waitcnt lgkmcnt(0)" ::: "memory");
    __builtin_amdgcn_s_setprio(1);
#pragma unroll
    for (int i = 0; i < 4; ++i)
#pragma unroll
      for (int j = 0; j < 2; ++j) {
        acc[i][j + 2] = mfma16(alo[i][0], bhi[j][0], acc[i][j + 2]);
        acc[i][j + 2] = mfma16(alo[i][1], bhi[j][1], acc[i][j + 2]);
      }
    __builtin_amdgcn_s_setprio(0);
    __builtin_amdgcn_s_barrier();

    // ---- phase 3: read a[4..7]; stage (T+2) Bq0,Bq1 ----
#pragma unroll
    for (int i = 0; i < 4; ++i) {
      ahi[i][0] = *(const bf16x8*)(Ac + aoff0 + (i + 4) * 1024);
      ahi[i][1] = *(const bf16x8*)(Ac + aoff1 + (i + 4) * 1024);
    }
    if (s2) { stB(cbuf, 0, T + 2); stB(cbuf, 1, T + 2); }
    __builtin_amdgcn_s_barrier();
    asm volatile("s_waitcnt lgkmcnt(0)" ::: "memory");
    __builtin_amdgcn_s_setprio(1);
#pragma unroll
    for (int i = 0; i < 4; ++i)
#pragma unroll
      for (int j = 0; j < 2; ++j) {
        acc[i + 4][j] = mfma16(ahi[i][0], blo[j][0], acc[i + 4][j]);
        acc[i + 4][j] = mfma16(ahi[i][1], blo[j][1], acc[i + 4][j]);
      }
    __builtin_amdgcn_s_setprio(0);
    __builtin_amdgcn_s_barrier();

    // ---- phase 4: no reads; stage (T+2) Aq1,Aq3; counted vmcnt ----
    if (s2) { stA(cbuf, 1, T + 2); stA(cbuf, 3, T + 2); }
    __builtin_amdgcn_s_barrier();
    __builtin_amdgcn_s_setprio(1);
#pragma unroll
    for (int i = 0; i < 4; ++i)
#pragma unroll
      for (int j = 0; j < 2; ++j) {
        acc[i + 4][j + 2] = mfma16(ahi[i][0], bhi[j][0], acc[i + 4][j + 2]);
        acc[i + 4][j + 2] = mfma16(ahi[i][1], bhi[j][1], acc[i + 4][j + 2]);
      }
    __builtin_amdgcn_s_setprio(0);
    if (s2)
      asm volatile("s_waitcnt vmcnt(6)" ::: "memory");  // (T+1) fully landed
    else
      asm volatile("s_waitcnt vmcnt(0)" ::: "memory");  // tail drain
    __builtin_amdgcn_s_barrier();
  }

  // epilogue: C/D layout col=l&15, row=(l>>4)*4+r
  const int row0 = bm * 256 + wr * 128 + lg * 4;
  const int col0 = bn * 256 + wc * 64 + lm;
#pragma unroll
  for (int j = 0; j < 4; ++j) {
    const int col = col0 + j * 16;
    const float bv = biasg[col];
#pragma unroll
    for (int i = 0; i < 8; ++i)
#pragma unroll
      for (int r = 0; r < 4; ++r) {
        const int row = row0 + i * 16 + r;
        const float v = acc[i][j][r] + bv;
        if (OUT_BF16)
          ((bf16*)Cv)[(size_t)mz * M * N + (size_t)row * N + col] = (bf16)v;
        else
          ((float*)Cv)[(size_t)mz * M * N + (size_t)row * N + col] = v;
      }
  }
}

// ---------------- in-place RMSNorm + RoPE on q,k head rows ----------------
__global__ __launch_bounds__(256) void rmsrope_kernel(bf16* __restrict__ qkv,
                                                      const float* __restrict__ qw,
                                                      const float* __restrict__ kw,
                                                      const float* __restrict__ cosT,
                                                      const float* __restrict__ sinT) {
  int gid = blockIdx.x * 4 + (threadIdx.x >> 6);
  int l = threadIdx.x & 63;
  int tok = gid >> 5;
  int slot = gid & 31;
  int mz = tok >> 12;
  bf16* p;
  const float* wv;
  if (slot < NHQ) {
    p = qkv + (size_t)tok * QKV_OUT + slot * HD;
    wv = qw + mz * HD;
  } else {
    p = qkv + (size_t)tok * QKV_OUT + HID + (slot - NHQ) * HD;
    wv = kw + mz * HD;
  }
  int d = l * 2;
  float x0 = (float)p[d];
  float x1 = (float)p[d + 1];
  float ss = x0 * x0 + x1 * x1;
#pragma unroll
  for (int m = 1; m < 64; m <<= 1) ss += __shfl_xor(ss, m);
  float rn = rsqrtf(ss * (1.0f / 128.0f) + 1e-6f);
  float n0 = x0 * rn * (wv[d] + 1.0f);
  float n1 = x1 * rn * (wv[d + 1] + 1.0f);
  float o0 = __shfl_xor(n0, 32);
  float o1 = __shfl_xor(n1, 32);
  int ci = d & 63;
  float2 cv = *reinterpret_cast<const float2*>(cosT + (size_t)tok * 64 + ci);
  float2 sv = *reinterpret_cast<const float2*>(sinT + (size_t)tok * 64 + ci);
  float sgn = (l < 32) ? -1.0f : 1.0f;
  p[d] = (bf16)(n0 * cv.x + sgn * o0 * sv.x);
  p[d + 1] = (bf16)(n1 * cv.y + sgn * o1 * sv.y);
}

// ---------------- block-diagonal GQA flash attention ----------------
__global__ __launch_bounds__(256) void attn_kernel(const bf16* __restrict__ qkv,
                                                   bf16* __restrict__ o) {
  constexpr float CEXP = 0.12753139626334912f;  // log2(e)/sqrt(128)
  const int tid = threadIdx.x;
  const int l = tid & 63;
  const int w = tid >> 6;
  const int sq = blockIdx.x;
  const int h = blockIdx.y;
  const int blk = blockIdx.z;
  const int kvh = h / 3;
  const int qtok0 = blk * CHUNKT + sq * 128 + w * 32;
  const int ktok0 = blk * CHUNKT;

  __shared__ bf16 KP[128 * 136];
  __shared__ bf16 Vt[128 * 136];

  bf16x8 qf[2][4];
#pragma unroll
  for (int i = 0; i < 2; ++i) {
    const bf16* qp =
        qkv + (size_t)(qtok0 + i * 16 + (l & 15)) * QKV_OUT + h * HD + (l >> 4) * 8;
#pragma unroll
    for (int c = 0; c < 4; ++c) qf[i][c] = *reinterpret_cast<const bf16x8*>(qp + c * 32);
  }

  f32x4 of[2][8] = {};
  float mrow[2][4], lrow[2][4];
#pragma unroll
  for (int i = 0; i < 2; ++i)
#pragma unroll
    for (int r = 0; r < 4; ++r) {
      mrow[i][r] = -1e30f;
      lrow[i][r] = 0.0f;
    }

  for (int c = 0; c < 8; ++c) {
    __syncthreads();
    const int kt = ktok0 + c * 128;
#pragma unroll
    for (int it = 0; it < 8; ++it) {
      int task = it * 256 + tid;
      int key = task >> 4, dc = task & 15;
      *reinterpret_cast<bf16x8*>(&KP[key * 136 + dc * 8]) =
          *reinterpret_cast<const bf16x8*>(
              qkv + (size_t)(kt + key) * QKV_OUT + HID + kvh * HD + dc * 8);
    }
#pragma unroll
    for (int it = 0; it < 8; ++it) {
      int task = it * 256 + tid;
      int key = task & 127, dc = task >> 7;
      bf16x8 vv = *reinterpret_cast<const bf16x8*>(
          qkv + (size_t)(kt + key) * QKV_OUT + HID + NHKV * HD + kvh * HD + dc * 8);
#pragma unroll
      for (int jj = 0; jj < 8; ++jj) Vt[(dc * 8 + jj) * 136 + key] = vv[jj];
    }
    __syncthreads();

    f32x4 sacc[2][8] = {};
#pragma unroll
    for (int kd = 0; kd < 4; ++kd) {
      bf16x8 kb[8];
#pragma unroll
      for (int j = 0; j < 8; ++j)
        kb[j] = *reinterpret_cast<const bf16x8*>(
            &KP[(j * 16 + (l & 15)) * 136 + kd * 32 + (l >> 4) * 8]);
#pragma unroll
      for (int i = 0; i < 2; ++i)
#pragma unroll
        for (int j = 0; j < 8; ++j) sacc[i][j] = mfma16(qf[i][kd], kb[j], sacc[i][j]);
    }

    float alpha[2][4];
#pragma unroll
    for (int i = 0; i < 2; ++i) {
#pragma unroll
      for (int r = 0; r < 4; ++r) {
        float mx = sacc[i][0][r];
#pragma unroll
        for (int j = 1; j < 8; ++j) mx = fmaxf(mx, sacc[i][j][r]);
        mx = fmaxf(mx, __shfl_xor(mx, 1));
        mx = fmaxf(mx, __shfl_xor(mx, 2));
        mx = fmaxf(mx, __shfl_xor(mx, 4));
        mx = fmaxf(mx, __shfl_xor(mx, 8));
        float mnew = fmaxf(mrow[i][r], mx);
        float al = exp2f((mrow[i][r] - mnew) * CEXP);
        mrow[i][r] = mnew;
        float ps = 0.0f;
#pragma unroll
        for (int j = 0; j < 8; ++j) {
          float pv = exp2f((sacc[i][j][r] - mnew) * CEXP);
          sacc[i][j][r] = pv;
          ps += pv;
        }
        ps += __shfl_xor(ps, 1);
        ps += __shfl_xor(ps, 2);
        ps += __shfl_xor(ps, 4);
        ps += __shfl_xor(ps, 8);
        lrow[i][r] = lrow[i][r] * al + ps;
        alpha[i][r] = al;
      }
    }
#pragma unroll
    for (int i = 0; i < 2; ++i)
#pragma unroll
      for (int j = 0; j < 8; ++j)
#pragma unroll
        for (int r = 0; r < 4; ++r) of[i][j][r] *= alpha[i][r];

    __syncthreads();
    bf16* P = KP + w * (32 * 136);
#pragma unroll
    for (int i = 0; i < 2; ++i)
#pragma unroll
      for (int j = 0; j < 8; ++j)
#pragma unroll
        for (int r = 0; r < 4; ++r)
          P[(i * 16 + (l >> 4) * 4 + r) * 136 + j * 16 + (l & 15)] = (bf16)sacc[i][j][r];

#pragma unroll
    for (int kk = 0; kk < 4; ++kk) {
      bf16x8 pa[2];
#pragma unroll
      for (int i = 0; i < 2; ++i)
        pa[i] = *reinterpret_cast<const bf16x8*>(
            &P[(i * 16 + (l & 15)) * 136 + kk * 32 + (l >> 4) * 8]);
#pragma unroll
      for (int j = 0; j < 8; ++j) {
        bf16x8 bv = *reinterpret_cast<const bf16x8*>(
            &Vt[(j * 16 + (l & 15)) * 136 + kk * 32 + (l >> 4) * 8]);
        of[0][j] = mfma16(pa[0], bv, of[0][j]);
        of[1][j] = mfma16(pa[1], bv, of[1][j]);
      }
    }
  }

#pragma unroll
  for (int i = 0; i < 2; ++i) {
#pragma unroll
    for (int r = 0; r < 4; ++r) {
      float inv = 1.0f / lrow[i][r];
      int row = qtok0 + i * 16 + (l >> 4) * 4 + r;
      bf16* orow = o + (size_t)row * HID + h * HD + (l & 15);
#pragma unroll
      for (int j = 0; j < 8; ++j) orow[j * 16] = (bf16)(of[i][j][r] * inv);
    }
  }
}

extern "C" void kernel_launch(void* const* d_in, const int* in_sizes, int n_in,
                              void* d_out, int out_size, void* d_ws, size_t ws_size,
                              hipStream_t stream) {
  const float* x = (const float*)d_in[0];
  const float* wqkv = (const float*)d_in[1];
  const float* bqkv = (const float*)d_in[2];
  const float* qnw = (const float*)d_in[3];
  const float* knw = (const float*)d_in[4];
  const float* cosT = (const float*)d_in[5];
  const float* sinT = (const float*)d_in[6];
  const float* wout = (const float*)d_in[7];
  const float* bout = (const float*)d_in[8];
  float* out = (float*)d_out;

  char* ws = (char*)d_ws;
  bf16* xb = (bf16*)ws;
  ws += (size_t)S_TOT * HID * 2;
  bf16* wqkvb = (bf16*)ws;
  ws += (size_t)2 * QKV_OUT * HID * 2;
  bf16* qkv = (bf16*)ws;
  bf16* ob = xb;        // region A reuse (x consumed by QKV GEMM)
  bf16* woutb = wqkvb;  // region B reuse (w_qkv consumed by QKV GEMM)

  cvt_kernel<<<2048, 256, 0, stream>>>(x, xb, S_TOT * HID / 4);
  cvt_kernel<<<2048, 256, 0, stream>>>(wqkv, wqkvb, 2 * QKV_OUT * HID / 4);

  gemm256<1><<<(QKV_OUT / 256) * (4096 / 256) * 2, 512, 0, stream>>>(
      xb, wqkvb, bqkv, qkv, 4096, QKV_OUT, HID);

  cvt_kernel<<<2048, 256, 0, stream>>>(wout, woutb, 2 * HID * HID / 4);

  rmsrope_kernel<<<(S_TOT * (NHQ + NHKV)) / 4, 256, 0, stream>>>(qkv, qnw, knw, cosT, sinT);

  attn_kernel<<<dim3(8, NHQ, 8), 256, 0, stream>>>(qkv, ob);

  gemm256<0><<<(HID / 256) * (4096 / 256) * 2, 512, 0, stream>>>(
      ob, woutb, bout, out, 4096, HID, HID);
}